// Round 6
// baseline (281.408 us; speedup 1.0000x reference)
//
#include <hip/hip_runtime.h>
#include <math.h>

#define NELEM    4096              // H*W
#define A_THREADS 256              // 4 waves cooperate on ONE row
#define HSTRIDE  260               // words; %4==0 (uint4-aligned), %32==4 (bank spread)
#define NHREP    8                 // replicas 0..3 = A (one per wave); 4..7 = B (diverged)
#define A_LDSW   (NELEM + NHREP * HSTRIDE)   // 4096 + 2080 words = 24.7 KB -> 6 blocks/CU

#define B_THREADS 256
#define B_BLOCKS  2048

typedef float v4f __attribute__((ext_vector_type(4)));

// order-preserving float->uint map (ascending), branchless
__device__ __forceinline__ unsigned f2ord(float f) {
    unsigned u = __float_as_uint(f);
    return u ^ ((unsigned)((int)u >> 31) | 0x80000000u);
}
__device__ __forceinline__ float ord2f(unsigned k) {
    return __uint_as_float(k ^ (~(unsigned)((int)k >> 31) | 0x80000000u));
}

// Canonical GCN wave64 inclusive add-scan in the VALU pipe via DPP.
__device__ __forceinline__ unsigned iscan_dpp(unsigned v) {
    v += (unsigned)__builtin_amdgcn_update_dpp(0, (int)v, 0x111, 0xF, 0xF, false);
    v += (unsigned)__builtin_amdgcn_update_dpp(0, (int)v, 0x112, 0xF, 0xF, false);
    v += (unsigned)__builtin_amdgcn_update_dpp(0, (int)v, 0x114, 0xF, 0xF, false);
    v += (unsigned)__builtin_amdgcn_update_dpp(0, (int)v, 0x118, 0xF, 0xF, false);
    v += (unsigned)__builtin_amdgcn_update_dpp(0, (int)v, 0x142, 0xA, 0xF, false);
    v += (unsigned)__builtin_amdgcn_update_dpp(0, (int)v, 0x143, 0xC, 0xF, false);
    return v;
}

struct Pick2 { unsigned a, b; };

// Reduce NR replicas of 256 bins (4 bins/lane), DPP-scan, locate ranks rA,rB.
// Wave-uniform packed result (bucket<<12)|localrank via ballot + v_readlane.
// All 4 waves run this redundantly on the same data -> identical results,
// no cross-wave broadcast needed.
template <int NR>
__device__ __forceinline__ Pick2 wave_pick2(const unsigned* region, int lane,
                                            unsigned rA, unsigned rB) {
    unsigned s0 = 0, s1 = 0, s2 = 0, s3 = 0;
    #pragma unroll
    for (int rep = 0; rep < NR; ++rep) {
        uint4 h = ((const uint4*)(region + rep * HSTRIDE))[lane];
        s0 += h.x; s1 += h.y; s2 += h.z; s3 += h.w;
    }
    unsigned tot = s0 + s1 + s2 + s3;
    unsigned inc = iscan_dpp(tot);
    unsigned ex  = inc - tot;
    unsigned base[4] = {ex, ex + s0, ex + s0 + s1, ex + s0 + s1 + s2};
    unsigned cnt[4]  = {s0, s1, s2, s3};
    unsigned resA = 0, resB = 0;
    bool fA = false, fB = false;
    #pragma unroll
    for (int j = 0; j < 4; ++j) {
        if (rA >= base[j] && rA < base[j] + cnt[j]) {
            resA = ((unsigned)(4 * lane + j) << 12) | (rA - base[j]); fA = true;
        }
        if (rB >= base[j] && rB < base[j] + cnt[j]) {
            resB = ((unsigned)(4 * lane + j) << 12) | (rB - base[j]); fB = true;
        }
    }
    unsigned long long mA = __ballot(fA);
    unsigned long long mB = __ballot(fB);
    Pick2 r;
    r.a = (unsigned)__builtin_amdgcn_readlane((int)resA, (int)(__ffsll((long long)mA) - 1));
    r.b = (unsigned)__builtin_amdgcn_readlane((int)resB, (int)(__ffsll((long long)mB) - 1));
    return r;
}

// ---------------- Phase A: per-row threshold (one block = one row) ----------
__global__ void __launch_bounds__(A_THREADS, 4)
thr_kernel(const float* __restrict__ x, const float* __restrict__ plogit,
           float* __restrict__ thr_out, int C) {
    __shared__ __align__(16) unsigned keys[NELEM];          // full row, 16 KB
    __shared__ __align__(16) unsigned hist[NHREP * HSTRIDE];

    const int tid  = threadIdx.x;
    const int wid  = tid >> 6;          // 0..3
    const int lane = tid & 63;
    const int row  = blockIdx.x;

    const float4* xr = (const float4*)(x + (size_t)row * NELEM);
    unsigned* myrep = hist + wid * HSTRIDE;
    const uint4 z4 = make_uint4(0u, 0u, 0u, 0u);

    // Zero own replica (bins 0..255 live in words 0..255; 256..259 are pad).
    ((uint4*)myrep)[lane] = z4;
    // Load own quarter: 4 float4/lane -> keys to LDS + pass-1 histogram.
    // Own replica was zeroed by THIS wave -> same-wave DS program order, no barrier.
    #pragma unroll
    for (int j = 0; j < 4; ++j) {
        int idx = wid * 256 + j * 64 + lane;      // float4 index within row
        float4 v = xr[idx];
        unsigned k0 = f2ord(v.x), k1 = f2ord(v.y), k2 = f2ord(v.z), k3 = f2ord(v.w);
        ((uint4*)keys)[idx] = make_uint4(k0, k1, k2, k3);
        atomicAdd(&myrep[k0 >> 24], 1u);
        atomicAdd(&myrep[k1 >> 24], 1u);
        atomicAdd(&myrep[k2 >> 24], 1u);
        atomicAdd(&myrep[k3 >> 24], 1u);
    }

    // Row-uniform scalars.
    float p0 = 1.0f / (1.0f + expf(-plogit[0]));
    float pc = 1.0f / (1.0f + expf(-plogit[row % C]));
    unsigned kLow  = (unsigned)min(max((int)((float)NELEM * (p0 - 0.02f)), 0), NELEM - 1);
    unsigned kHigh = (unsigned)min(max((int)((float)NELEM * (p0 + 0.02f)), 0), NELEM - 1);

    __syncthreads();
    Pick2 p1 = wave_pick2<4>(hist, lane, kLow, kHigh);
    unsigned bA = p1.a >> 12, bB = p1.b >> 12;
    unsigned prefA = bA << 24, rA = p1.a & 0xFFFu;
    unsigned prefB = bB << 24, rB = p1.b & 0xFFFu;
    unsigned known = 0xFF000000u;
    bool diverged = (bA != bB);         // identical in all waves

    // Passes 2..4: keys re-scanned from LDS (wave's own quarter), counts into
    // wave-private replica(s); picks sum the 4 replicas.
    #pragma unroll 1
    for (int shift = 16; shift >= 0; shift -= 8) {
        __syncthreads();                 // all waves done READING hist
        ((uint4*)myrep)[lane] = z4;
        if (diverged) ((uint4*)(myrep + 4 * HSTRIDE))[lane] = z4;
        #pragma unroll
        for (int j = 0; j < 4; ++j) {
            uint4 kk4 = ((const uint4*)keys)[wid * 256 + j * 64 + lane];
            unsigned ks[4] = {kk4.x, kk4.y, kk4.z, kk4.w};
            #pragma unroll
            for (int e = 0; e < 4; ++e) {
                unsigned kk = ks[e];
                unsigned km = kk & known;
                if (!diverged) {
                    if (km == prefA)
                        atomicAdd(&myrep[(kk >> shift) & 0xFFu], 1u);
                } else {
                    bool isB = (km == prefB);
                    if ((km == prefA) | isB)
                        atomicAdd(myrep + (isB ? 4 * HSTRIDE : 0)
                                        + ((kk >> shift) & 0xFFu), 1u);
                }
            }
        }
        __syncthreads();                 // all waves' counts visible
        if (!diverged) {
            Pick2 p = wave_pick2<4>(hist, lane, rA, rB);
            unsigned cA = p.a >> 12, cB = p.b >> 12;
            prefA |= cA << shift;  rA = p.a & 0xFFFu;
            prefB |= cB << shift;  rB = p.b & 0xFFFu;
            diverged = (cA != cB);
        } else {
            unsigned pa = wave_pick2<4>(hist, lane, rA, rA).a;
            unsigned pb = wave_pick2<4>(hist + 4 * HSTRIDE, lane, rB, rB).a;
            prefA |= (pa >> 12) << shift;  rA = pa & 0xFFFu;
            prefB |= (pb >> 12) << shift;  rB = pb & 0xFFFu;
        }
        known |= 0xFFu << shift;
    }

    if (tid == 0) {
        float xlow  = ord2f(prefA);
        float xhigh = ord2f(prefB);
        thr_out[row] = xlow + (xhigh - xlow) * pc;
    }
}

// ---------------- Phase B: streaming relu(x - thr[row]) --------------------
__global__ void __launch_bounds__(B_THREADS)
relu_kernel(const float* __restrict__ x, const float* __restrict__ thr,
            float* __restrict__ out, long total4) {
    long i = (long)blockIdx.x * B_THREADS + threadIdx.x;
    const long stride = (long)gridDim.x * B_THREADS;
    const float4* xv = (const float4*)x;
    v4f* ov = (v4f*)out;
    for (; i < total4; i += stride) {
        float4 v = xv[i];
        // 1024 float4 per row; wave (64 lanes) never straddles a row boundary
        float t = thr[i >> 10];
        v4f o;
        o.x = fmaxf(v.x - t, 0.0f);
        o.y = fmaxf(v.y - t, 0.0f);
        o.z = fmaxf(v.z - t, 0.0f);
        o.w = fmaxf(v.w - t, 0.0f);
        __builtin_nontemporal_store(o, ov + i);
    }
}

extern "C" void kernel_launch(void* const* d_in, const int* in_sizes, int n_in,
                              void* d_out, int out_size, void* d_ws, size_t ws_size,
                              hipStream_t stream) {
    const float* x      = (const float*)d_in[0];
    const float* plogit = (const float*)d_in[1];
    float* out          = (float*)d_out;
    float* thr          = (float*)d_ws;            // rows * 4 bytes (32 KB)
    int C    = in_sizes[1];                        // 256
    int rows = in_sizes[0] / NELEM;                // 8192
    thr_kernel<<<rows, A_THREADS, 0, stream>>>(x, plogit, thr, C);
    long total4 = (long)rows * (NELEM / 4);
    relu_kernel<<<B_BLOCKS, B_THREADS, 0, stream>>>(x, thr, out, total4);
}